// Round 6
// baseline (187.117 us; speedup 1.0000x reference)
//
#include <hip/hip_runtime.h>

#define N_NODES 50000
#define N_EDGES 800000
#define D 128
#define CAP 64
#define NPB 512        // nodes per bin: bin = dst >> 9
#define NBIN 98        // ceil(50000/512)
#define BIN_CAP 12288  // per-bin edge capacity (mean 8163)
#define EPB 4096       // edges per binp block

typedef __attribute__((ext_vector_type(8))) short s16x8;
typedef __attribute__((ext_vector_type(8))) unsigned short u16x8;
typedef __attribute__((ext_vector_type(4))) unsigned short u16x4;
typedef __attribute__((ext_vector_type(4))) float f32x4;

__device__ __forceinline__ unsigned short f2bf(float f) {
    unsigned u = __builtin_bit_cast(unsigned, f);
    return (unsigned short)((u + 0x7FFFu + ((u >> 16) & 1u)) >> 16);
}
__device__ __forceinline__ float bf2f(unsigned short h) {
    return __builtin_bit_cast(float, (unsigned)h << 16);
}

// ---------------------------------------------------------------------------
__global__ void initp_kernel(const int* __restrict__ ei, int* __restrict__ flag,
                             int* __restrict__ bin_cnt) {
    if (threadIdx.x < 128) bin_cnt[threadIdx.x] = 0;
    __shared__ int any;
    if (threadIdx.x == 0) any = 0;
    __syncthreads();
    if (ei[2 * threadIdx.x + 1] != 0) atomicOr(&any, 1);
    __syncthreads();
    if (threadIdx.x == 0) flag[0] = any;
}

__global__ void initc_kernel(const int* __restrict__ ei, int* __restrict__ flag,
                             int* __restrict__ cnt) {
    int i = blockIdx.x * 256 + threadIdx.x;
    if (i < 50048) cnt[i] = 0;
    if (blockIdx.x == 0) {
        __shared__ int any;
        if (threadIdx.x == 0) any = 0;
        __syncthreads();
        if (ei[2 * threadIdx.x + 1] != 0) atomicOr(&any, 1);
        __syncthreads();
        if (threadIdx.x == 0) flag[0] = any;
    }
}

__device__ __forceinline__ int load_src(const int* ei, int is32, int e) {
    return is32 ? ei[e] : ei[2 * e];
}
__device__ __forceinline__ int load_dst(const int* ei, int is32, int e) {
    return is32 ? ei[N_EDGES + e] : ei[2 * N_EDGES + 2 * e];
}

// f32 -> bf16 row-copy (x -> xb).
__global__ void tobf_kernel(const float* __restrict__ in, unsigned short* __restrict__ out,
                            int n8) {
    int t = blockIdx.x * 256 + threadIdx.x;
    if (t >= n8) return;
    float4 a = *(const float4*)(in + (size_t)t * 8);
    float4 b = *(const float4*)(in + (size_t)t * 8 + 4);
    u16x8 o;
    o[0] = f2bf(a.x); o[1] = f2bf(a.y); o[2] = f2bf(a.z); o[3] = f2bf(a.w);
    o[4] = f2bf(b.x); o[5] = f2bf(b.y); o[6] = f2bf(b.z); o[7] = f2bf(b.w);
    *(u16x8*)(out + (size_t)t * 8) = o;
}

// ---------------------------------------------------------------------------
// Pass 1: bin edges by dst>>9 into 98 global bins; packed (dst16|src16).
__global__ __launch_bounds__(256) void binp_kernel(const int* __restrict__ ei,
                                                   const int* __restrict__ flag,
                                                   int* __restrict__ bin_cnt,
                                                   unsigned* __restrict__ bins) {
    __shared__ unsigned sBuf[EPB];
    __shared__ int bcnt[128], brun[128], bpos[128], gbase[128];
    int tid = threadIdx.x;
    int blk = blockIdx.x;
    int e0 = blk * EPB + tid * 16;
    int nblk = N_EDGES - blk * EPB;
    if (nblk > EPB) nblk = EPB;
    bool valid = (tid * 16) < nblk;
    if (tid < 128) bcnt[tid] = 0;
    __syncthreads();
    unsigned packed[16];
    if (valid) {
        int is32 = flag[0];
        if (is32) {
            const int4* ps = (const int4*)(ei + e0);
            const int4* pd = (const int4*)(ei + N_EDGES + e0);
#pragma unroll
            for (int q = 0; q < 4; ++q) {
                int4 s = ps[q], d = pd[q];
                packed[q * 4 + 0] = ((unsigned)d.x << 16) | (unsigned)s.x;
                packed[q * 4 + 1] = ((unsigned)d.y << 16) | (unsigned)s.y;
                packed[q * 4 + 2] = ((unsigned)d.z << 16) | (unsigned)s.z;
                packed[q * 4 + 3] = ((unsigned)d.w << 16) | (unsigned)s.w;
            }
        } else {
            const int4* ps = (const int4*)(ei + 2 * (size_t)e0);
            const int4* pd = (const int4*)(ei + 2 * (size_t)N_EDGES + 2 * (size_t)e0);
#pragma unroll
            for (int q = 0; q < 8; ++q) {
                int4 s = ps[q], d = pd[q];
                packed[q * 2 + 0] = ((unsigned)d.x << 16) | (unsigned)s.x;
                packed[q * 2 + 1] = ((unsigned)d.z << 16) | (unsigned)s.z;
            }
        }
#pragma unroll
        for (int k = 0; k < 16; ++k) atomicAdd(&bcnt[packed[k] >> 25], 1);
    }
    __syncthreads();
    if (tid < 64) {
        int a = bcnt[2 * tid], b = bcnt[2 * tid + 1];
        int s = a + b;
        int incl = s;
#pragma unroll
        for (int o = 1; o < 64; o <<= 1) {
            int t = __shfl_up(incl, o, 64);
            if (tid >= o) incl += t;
        }
        int pref = incl - s;
        brun[2 * tid] = pref;
        brun[2 * tid + 1] = pref + a;
        bpos[2 * tid] = pref;
        bpos[2 * tid + 1] = pref + a;
    }
    __syncthreads();
    if (valid) {
#pragma unroll
        for (int k = 0; k < 16; ++k) {
            int b = packed[k] >> 25;
            int slot = atomicAdd(&bpos[b], 1);
            sBuf[slot] = packed[k];
        }
    }
    __syncthreads();
    if (tid < 128) {
        int n = bcnt[tid];
        gbase[tid] = n > 0 ? atomicAdd(&bin_cnt[tid], n) : 0;
    }
    __syncthreads();
    for (int i = tid; i < nblk; i += 256) {
        unsigned p = sBuf[i];
        int b = p >> 25;
        int gpos = gbase[b] + (i - brun[b]);
        if (gpos < BIN_CAP) bins[(size_t)b * BIN_CAP + gpos] = p;
    }
}

// Pass 2: one block per bin; buckets in LDS; dense coalesced write-out.
__global__ __launch_bounds__(256) void unbin_kernel(const int* __restrict__ bin_cnt,
                                                    const unsigned* __restrict__ bins,
                                                    int* __restrict__ cnt,
                                                    unsigned short* __restrict__ srcs16) {
    __shared__ unsigned short buck[NPB * CAP];
    __shared__ int lcnt[NPB];
    int tid = threadIdx.x;
    int bn = blockIdx.x;
    int nbase = bn * NPB;
    for (int i = tid; i < NPB; i += 256) lcnt[i] = 0;
    __syncthreads();
    int nE = bin_cnt[bn];
    if (nE > BIN_CAP) nE = BIN_CAP;
    for (int i = tid; i < nE; i += 256) {
        unsigned p = bins[(size_t)bn * BIN_CAP + i];
        int local = (int)(p >> 16) - nbase;
        if ((unsigned)local < NPB) {
            int slot = atomicAdd(&lcnt[local], 1);
            if (slot < CAP) buck[local * CAP + slot] = (unsigned short)(p & 0xFFFFu);
        }
    }
    __syncthreads();
    int nlim = N_NODES - nbase;
    if (nlim > NPB) nlim = NPB;
    const uint4* sb = (const uint4*)buck;
    uint4* go = (uint4*)(srcs16 + (size_t)nbase * CAP);
    int n4 = nlim * 8;
    for (int i = tid; i < n4; i += 256) go[i] = sb[i];
    for (int i = tid; i < nlim; i += 256) cnt[nbase + i] = lcnt[i];
}

// ---------------------------------------------------------------------------
// W2t = [Wl;Wr]^T as bf16 hi(truncate)/lo(RN residual), layout [col(128)][k(256)].
__global__ void prep_w(const float* __restrict__ Wl, const float* __restrict__ Wr,
                       unsigned short* __restrict__ hi, unsigned short* __restrict__ lo) {
    int c = blockIdx.x;
    int k = threadIdx.x;
    float v = (k < 128) ? Wl[(size_t)k * 128 + c] : Wr[(size_t)(k - 128) * 128 + c];
    unsigned u = __builtin_bit_cast(unsigned, v);
    unsigned short h = (unsigned short)(u >> 16);
    float hf = __builtin_bit_cast(float, u & 0xFFFF0000u);
    float r = v - hf;
    unsigned ur = __builtin_bit_cast(unsigned, r);
    unsigned short l = (unsigned short)((ur + 0x7FFFu + ((ur >> 16) & 1u)) >> 16);
    hi[c * 256 + k] = h;
    lo[c * 256 + k] = l;
}

// ---------------------------------------------------------------------------
// FUSED layer: gather-mean (into LDS) + dual-matmul + bias (+relu).
// MODE 1: gather bf16 xb; root = f32 x (hi/lo 3-term); out = bf16 h -> Cb.
// MODE 2: gather bf16 h;  root = bf16 h (2-term);      out = f32 -> C.
// LDS: sAgg[64][128], sXhi[64][128], (MODE1) sXlo[64][128]; bf16, XOR-swizzled
// 16B chunks: phys_chunk = logical_chunk ^ (row&7) -> conflict-free frag reads.
// One __syncthreads total.
template <int MODE>
__global__ __launch_bounds__(256) void layer_kernel(const unsigned short* __restrict__ feat,
                                                    const float* __restrict__ Xf,
                                                    const unsigned short* __restrict__ Xb,
                                                    const int* __restrict__ cnt,
                                                    const unsigned short* __restrict__ srcs16,
                                                    const unsigned short* __restrict__ Wthi,
                                                    const unsigned short* __restrict__ Wtlo,
                                                    const float* __restrict__ bias,
                                                    float* __restrict__ C,
                                                    unsigned short* __restrict__ Cb) {
    extern __shared__ unsigned short smem[];
    unsigned short* sAgg = smem;            // 8192 ushorts
    unsigned short* sXhi = smem + 8192;     // 8192
    unsigned short* sXlo = smem + 16384;    // MODE1 only

    int r0 = blockIdx.x * 64;
    int tid = threadIdx.x;
    int lane = tid & 63, wid = tid >> 6;
    int wm = wid >> 1, wn = wid & 1;
    int l15 = lane & 15, khalf = lane >> 4;

    // ---- issue root-row loads early (held in regs through the gather)
    int rr_ = tid >> 2, kq = tid & 3;
    int rowX = r0 + rr_;
    float vX[32];
    u16x8 vB[4];
    if (MODE == 1) {
        if (rowX < N_NODES) {
            const float* p = Xf + (size_t)rowX * D + kq * 32;
#pragma unroll
            for (int i = 0; i < 8; ++i) {
                float4 t4 = *(const float4*)(p + i * 4);
                vX[i * 4 + 0] = t4.x; vX[i * 4 + 1] = t4.y;
                vX[i * 4 + 2] = t4.z; vX[i * 4 + 3] = t4.w;
            }
        } else {
#pragma unroll
            for (int i = 0; i < 32; ++i) vX[i] = 0.f;
        }
    } else {
        if (rowX < N_NODES) {
            const u16x8* p = (const u16x8*)(Xb + (size_t)rowX * D + kq * 32);
#pragma unroll
            for (int i = 0; i < 4; ++i) vB[i] = p[i];
        } else {
            u16x8 z = {};
#pragma unroll
            for (int i = 0; i < 4; ++i) vB[i] = z;
        }
    }

    // ---- gather phase: wave wid owns nodes nb..nb+15
    {
        int nb = r0 + wid * 16;
        int q = lane >> 4, c16 = lane & 15;
        int nd = nb + (lane & 15);
        int d16 = (nd < N_NODES) ? cnt[nd] : 0;
        int idx_cur = srcs16[(size_t)nb * CAP + lane];
        for (int i = 0; i < 16; ++i) {
            int idx_next = (i < 15) ? (int)srcs16[(size_t)(nb + i + 1) * CAP + lane] : 0;
            int deg = __shfl(d16, i, 64);
            int dd = deg < CAP ? deg : CAP;
            float acc[8] = {};
            for (int j = 0; j < dd; j += 16) {
                int e[4];
                float m[4];
#pragma unroll
                for (int u = 0; u < 4; ++u) {
                    int jj = j + u * 4 + q;
                    int es = __shfl(idx_cur, jj, 64);
                    bool val = jj < dd;
                    e[u] = val ? es : 0;
                    m[u] = val ? 1.f : 0.f;
                }
                u16x8 v[4];
#pragma unroll
                for (int u = 0; u < 4; ++u)
                    v[u] = *((const u16x8*)(feat + (size_t)e[u] * D) + c16);
#pragma unroll
                for (int u = 0; u < 4; ++u)
#pragma unroll
                    for (int k2 = 0; k2 < 8; ++k2)
                        acc[k2] += bf2f((unsigned short)v[u][k2]) * m[u];
            }
#pragma unroll
            for (int k2 = 0; k2 < 8; ++k2) {
                acc[k2] += __shfl_xor(acc[k2], 16, 64);
                acc[k2] += __shfl_xor(acc[k2], 32, 64);
            }
            if (q == 0) {
                float s = deg > 0 ? 1.f / (float)deg : 0.f;
                u16x8 o;
#pragma unroll
                for (int k2 = 0; k2 < 8; ++k2) o[k2] = f2bf(acc[k2] * s);
                int row = wid * 16 + i;
                int chunk = c16 ^ (row & 7);
                *(u16x8*)&sAgg[row * 128 + chunk * 8] = o;
            }
            idx_cur = idx_next;
        }
    }

    // ---- root convert + LDS write (swizzled)
    if (MODE == 1) {
#pragma unroll
        for (int cch = 0; cch < 4; ++cch) {
            u16x8 h8, l8;
#pragma unroll
            for (int i = 0; i < 8; ++i) {
                float f = vX[cch * 8 + i];
                unsigned u = __builtin_bit_cast(unsigned, f);
                h8[i] = (unsigned short)(u >> 16);
                float hf = __builtin_bit_cast(float, u & 0xFFFF0000u);
                float rres = f - hf;
                unsigned ur = __builtin_bit_cast(unsigned, rres);
                l8[i] = (unsigned short)((ur + 0x7FFFu + ((ur >> 16) & 1u)) >> 16);
            }
            int chunk = (kq * 4 + cch) ^ (rr_ & 7);
            *(u16x8*)&sXhi[rr_ * 128 + chunk * 8] = h8;
            *(u16x8*)&sXlo[rr_ * 128 + chunk * 8] = l8;
        }
    } else {
#pragma unroll
        for (int cch = 0; cch < 4; ++cch) {
            int chunk = (kq * 4 + cch) ^ (rr_ & 7);
            *(u16x8*)&sXhi[rr_ * 128 + chunk * 8] = vB[cch];
        }
    }
    __syncthreads();

    // ---- GEMM: phase 0 = agg (2-term), phase 1 = root (MODE1 3-term / MODE2 2-term)
    f32x4 acc[2][4] = {};
#pragma unroll
    for (int kc2 = 0; kc2 < 4; ++kc2) {
        s16x8 aH[2];
#pragma unroll
        for (int mf = 0; mf < 2; ++mf) {
            int rr = wm * 32 + mf * 16 + l15;
            int chunk = (kc2 * 4 + khalf) ^ (rr & 7);
            aH[mf] = *(const s16x8*)&sAgg[rr * 128 + chunk * 8];
        }
#pragma unroll
        for (int nf = 0; nf < 4; ++nf) {
            int cc = wn * 64 + nf * 16 + l15;
            size_t bo = (size_t)cc * 256 + kc2 * 32 + khalf * 8;
            s16x8 bH = *(const s16x8*)(Wthi + bo);
            s16x8 bL = *(const s16x8*)(Wtlo + bo);
#pragma unroll
            for (int mf = 0; mf < 2; ++mf) {
                acc[mf][nf] = __builtin_amdgcn_mfma_f32_16x16x32_bf16(aH[mf], bH, acc[mf][nf], 0, 0, 0);
                acc[mf][nf] = __builtin_amdgcn_mfma_f32_16x16x32_bf16(aH[mf], bL, acc[mf][nf], 0, 0, 0);
            }
        }
    }
#pragma unroll
    for (int kc2 = 0; kc2 < 4; ++kc2) {
        s16x8 aH[2], aL[2];
#pragma unroll
        for (int mf = 0; mf < 2; ++mf) {
            int rr = wm * 32 + mf * 16 + l15;
            int chunk = (kc2 * 4 + khalf) ^ (rr & 7);
            aH[mf] = *(const s16x8*)&sXhi[rr * 128 + chunk * 8];
            if (MODE == 1) aL[mf] = *(const s16x8*)&sXlo[rr * 128 + chunk * 8];
        }
#pragma unroll
        for (int nf = 0; nf < 4; ++nf) {
            int cc = wn * 64 + nf * 16 + l15;
            size_t bo = (size_t)cc * 256 + 128 + kc2 * 32 + khalf * 8;
            s16x8 bH = *(const s16x8*)(Wthi + bo);
            s16x8 bL = *(const s16x8*)(Wtlo + bo);
#pragma unroll
            for (int mf = 0; mf < 2; ++mf) {
                acc[mf][nf] = __builtin_amdgcn_mfma_f32_16x16x32_bf16(aH[mf], bH, acc[mf][nf], 0, 0, 0);
                if (MODE == 1)
                    acc[mf][nf] = __builtin_amdgcn_mfma_f32_16x16x32_bf16(aL[mf], bH, acc[mf][nf], 0, 0, 0);
                acc[mf][nf] = __builtin_amdgcn_mfma_f32_16x16x32_bf16(aH[mf], bL, acc[mf][nf], 0, 0, 0);
            }
        }
    }

    // ---- epilogue: C/D layout col=lane&15, row=(lane>>4)*4+reg (m89-verified)
#pragma unroll
    for (int mf = 0; mf < 2; ++mf)
#pragma unroll
        for (int nf = 0; nf < 4; ++nf) {
            int col = wn * 64 + nf * 16 + l15;
            float b = bias[col];
#pragma unroll
            for (int r = 0; r < 4; ++r) {
                int row = r0 + wm * 32 + mf * 16 + khalf * 4 + r;
                if (row < N_NODES) {
                    float o = acc[mf][nf][r] + b;
                    if (MODE == 1) {
                        o = fmaxf(o, 0.f);
                        Cb[(size_t)row * D + col] = f2bf(o);
                    } else {
                        C[(size_t)row * D + col] = o;
                    }
                }
            }
        }
}

// ---------------------------------------------------------------------------
// ---- compact CSR fallback kernels (only if ws too small) -------------------
__global__ void hist_kernel(const int* __restrict__ ei, const int* __restrict__ flag,
                            int* __restrict__ cnt) {
    int e = blockIdx.x * blockDim.x + threadIdx.x;
    if (e >= N_EDGES) return;
    int is32 = flag[0];
    atomicAdd(&cnt[load_dst(ei, is32, e)], 1);
}

__global__ __launch_bounds__(1024) void scan_kernel(int* __restrict__ cnt_cur,
                                                    int* __restrict__ off) {
    __shared__ int wsum[16];
    __shared__ int woff[16];
    __shared__ int carry;
    __shared__ int tile_tot;
    int lane = threadIdx.x & 63;
    int wid = threadIdx.x >> 6;
    if (threadIdx.x == 0) carry = 0;
    __syncthreads();
    for (int base = 0; base < N_NODES; base += 1024) {
        int i = base + threadIdx.x;
        int v = (i < N_NODES) ? cnt_cur[i] : 0;
        int incl = v;
#pragma unroll
        for (int o = 1; o < 64; o <<= 1) {
            int t = __shfl_up(incl, o, 64);
            if (lane >= o) incl += t;
        }
        if (lane == 63) wsum[wid] = incl;
        __syncthreads();
        if (wid == 0 && lane < 16) {
            int t = wsum[lane];
            int inc2 = t;
#pragma unroll
            for (int o = 1; o < 16; o <<= 1) {
                int u = __shfl_up(inc2, o, 64);
                if (lane >= o) inc2 += u;
            }
            woff[lane] = inc2 - t;
            if (lane == 15) tile_tot = inc2;
        }
        __syncthreads();
        int c = carry;
        if (i < N_NODES) {
            int o = c + woff[wid] + (incl - v);
            off[i] = o;
            cnt_cur[i] = o;
        }
        __syncthreads();
        if (threadIdx.x == 0) carry = c + tile_tot;
        __syncthreads();
    }
    if (threadIdx.x == 0) off[N_NODES] = carry;
}

__global__ void fillc_kernel(const int* __restrict__ ei, const int* __restrict__ flag,
                             int* __restrict__ cur, int* __restrict__ srcs) {
    int e = blockIdx.x * blockDim.x + threadIdx.x;
    if (e >= N_EDGES) return;
    int is32 = flag[0];
    int d = load_dst(ei, is32, e);
    int p = atomicAdd(&cur[d], 1);
    srcs[p] = load_src(ei, is32, e);
}

__global__ __launch_bounds__(256) void aggc_kernel(const unsigned short* __restrict__ feat,
                                                   const int* __restrict__ off,
                                                   const int* __restrict__ srcs,
                                                   unsigned short* __restrict__ agg) {
    int node = blockIdx.x * 4 + (threadIdx.x >> 6);
    if (node >= N_NODES) return;
    int lane = threadIdx.x & 63;
    int half = lane >> 5;
    int c8 = lane & 31;
    int s0 = off[node], s1 = off[node + 1];
    int deg = s1 - s0;
    float a0 = 0.f, a1 = 0.f, a2 = 0.f, a3 = 0.f;
    for (int j = s0; j < s1; j += 2) {
        int jj = j + half;
        if (jj < s1) {
            int e = srcs[jj];
            u16x4 v = *((const u16x4*)(feat + (size_t)e * D) + c8);
            a0 += bf2f((unsigned short)v[0]);
            a1 += bf2f((unsigned short)v[1]);
            a2 += bf2f((unsigned short)v[2]);
            a3 += bf2f((unsigned short)v[3]);
        }
    }
    a0 += __shfl_xor(a0, 32, 64);
    a1 += __shfl_xor(a1, 32, 64);
    a2 += __shfl_xor(a2, 32, 64);
    a3 += __shfl_xor(a3, 32, 64);
    if (half == 0) {
        float s = deg > 0 ? 1.f / (float)deg : 0.f;
        u16x4 o;
        o[0] = f2bf(a0 * s); o[1] = f2bf(a1 * s);
        o[2] = f2bf(a2 * s); o[3] = f2bf(a3 * s);
        *((u16x4*)(agg + (size_t)node * D) + c8) = o;
    }
}

// fallback standalone GEMM (old structure, pad-136 LDS)
template <int MODE>
__global__ __launch_bounds__(256) void mm_kernel(const unsigned short* __restrict__ Agb,
                                                 const float* __restrict__ X,
                                                 const unsigned short* __restrict__ Xb,
                                                 const unsigned short* __restrict__ Wthi,
                                                 const unsigned short* __restrict__ Wtlo,
                                                 const float* __restrict__ bias,
                                                 float* __restrict__ C,
                                                 unsigned short* __restrict__ Cb) {
    __shared__ __align__(16) unsigned short sAhi[64][136];
    __shared__ __align__(16) unsigned short sAlo[64][136];
    int r0 = blockIdx.x * 64;
    int tid = threadIdx.x;
    int lane = tid & 63, wid = tid >> 6;
    int wm = wid >> 1, wn = wid & 1;
    int l15 = lane & 15, khalf = lane >> 4;
    f32x4 acc[2][4] = {};

    {
        int r = tid >> 2, kq = tid & 3;
        int row = r0 + r;
        if (row < N_NODES) {
            const u16x8* p = (const u16x8*)(Agb + (size_t)row * D + kq * 32);
#pragma unroll
            for (int i = 0; i < 4; ++i) *(u16x8*)&sAhi[r][kq * 32 + i * 8] = p[i];
        } else {
            u16x8 z = {};
#pragma unroll
            for (int i = 0; i < 4; ++i) *(u16x8*)&sAhi[r][kq * 32 + i * 8] = z;
        }
    }
    __syncthreads();
#pragma unroll
    for (int kc2 = 0; kc2 < 4; ++kc2) {
        s16x8 aH[2];
#pragma unroll
        for (int mf = 0; mf < 2; ++mf)
            aH[mf] = *(const s16x8*)&sAhi[wm * 32 + mf * 16 + l15][kc2 * 32 + khalf * 8];
#pragma unroll
        for (int nf = 0; nf < 4; ++nf) {
            int cc = wn * 64 + nf * 16 + l15;
            size_t bo = (size_t)cc * 256 + kc2 * 32 + khalf * 8;
            s16x8 bH = *(const s16x8*)(Wthi + bo);
            s16x8 bL = *(const s16x8*)(Wtlo + bo);
#pragma unroll
            for (int mf = 0; mf < 2; ++mf) {
                acc[mf][nf] = __builtin_amdgcn_mfma_f32_16x16x32_bf16(aH[mf], bH, acc[mf][nf], 0, 0, 0);
                acc[mf][nf] = __builtin_amdgcn_mfma_f32_16x16x32_bf16(aH[mf], bL, acc[mf][nf], 0, 0, 0);
            }
        }
    }
    __syncthreads();
    if (MODE == 1) {
        int r = tid >> 2, kq = tid & 3;
        int row = r0 + r;
        const float* p = X + (size_t)row * D + kq * 32;
        float v[32];
        if (row < N_NODES) {
#pragma unroll
            for (int i = 0; i < 8; ++i) {
                float4 t4 = *(const float4*)(p + i * 4);
                v[i * 4 + 0] = t4.x; v[i * 4 + 1] = t4.y;
                v[i * 4 + 2] = t4.z; v[i * 4 + 3] = t4.w;
            }
        } else {
#pragma unroll
            for (int i = 0; i < 32; ++i) v[i] = 0.f;
        }
#pragma unroll
        for (int cch = 0; cch < 4; ++cch) {
            u16x8 h8, l8;
#pragma unroll
            for (int i = 0; i < 8; ++i) {
                float f = v[cch * 8 + i];
                unsigned u = __builtin_bit_cast(unsigned, f);
                h8[i] = (unsigned short)(u >> 16);
                float hf = __builtin_bit_cast(float, u & 0xFFFF0000u);
                float rres = f - hf;
                unsigned ur = __builtin_bit_cast(unsigned, rres);
                l8[i] = (unsigned short)((ur + 0x7FFFu + ((ur >> 16) & 1u)) >> 16);
            }
            *(u16x8*)&sAhi[r][kq * 32 + cch * 8] = h8;
            *(u16x8*)&sAlo[r][kq * 32 + cch * 8] = l8;
        }
    } else {
        int r = tid >> 2, kq = tid & 3;
        int row = r0 + r;
        if (row < N_NODES) {
            const u16x8* p = (const u16x8*)(Xb + (size_t)row * D + kq * 32);
#pragma unroll
            for (int i = 0; i < 4; ++i) *(u16x8*)&sAhi[r][kq * 32 + i * 8] = p[i];
        } else {
            u16x8 z = {};
#pragma unroll
            for (int i = 0; i < 4; ++i) *(u16x8*)&sAhi[r][kq * 32 + i * 8] = z;
        }
    }
    __syncthreads();
#pragma unroll
    for (int kc2 = 0; kc2 < 4; ++kc2) {
        s16x8 aH[2], aL[2];
#pragma unroll
        for (int mf = 0; mf < 2; ++mf) {
            int rr = wm * 32 + mf * 16 + l15;
            aH[mf] = *(const s16x8*)&sAhi[rr][kc2 * 32 + khalf * 8];
            if (MODE == 1) aL[mf] = *(const s16x8*)&sAlo[rr][kc2 * 32 + khalf * 8];
        }
#pragma unroll
        for (int nf = 0; nf < 4; ++nf) {
            int cc = wn * 64 + nf * 16 + l15;
            size_t bo = (size_t)cc * 256 + 128 + kc2 * 32 + khalf * 8;
            s16x8 bH = *(const s16x8*)(Wthi + bo);
            s16x8 bL = *(const s16x8*)(Wtlo + bo);
#pragma unroll
            for (int mf = 0; mf < 2; ++mf) {
                acc[mf][nf] = __builtin_amdgcn_mfma_f32_16x16x32_bf16(aH[mf], bH, acc[mf][nf], 0, 0, 0);
                if (MODE == 1)
                    acc[mf][nf] = __builtin_amdgcn_mfma_f32_16x16x32_bf16(aL[mf], bH, acc[mf][nf], 0, 0, 0);
                acc[mf][nf] = __builtin_amdgcn_mfma_f32_16x16x32_bf16(aH[mf], bL, acc[mf][nf], 0, 0, 0);
            }
        }
    }
#pragma unroll
    for (int mf = 0; mf < 2; ++mf)
#pragma unroll
        for (int nf = 0; nf < 4; ++nf) {
            int col = wn * 64 + nf * 16 + l15;
            float b = bias[col];
#pragma unroll
            for (int r = 0; r < 4; ++r) {
                int row = r0 + wm * 32 + mf * 16 + khalf * 4 + r;
                if (row < N_NODES) {
                    float o = acc[mf][nf][r] + b;
                    if (MODE == 1) {
                        o = fmaxf(o, 0.f);
                        Cb[(size_t)row * D + col] = f2bf(o);
                    } else {
                        C[(size_t)row * D + col] = o;
                    }
                }
            }
        }
}

// ---------------------------------------------------------------------------
extern "C" void kernel_launch(void* const* d_in, const int* in_sizes, int n_in,
                              void* d_out, int out_size, void* d_ws, size_t ws_size,
                              hipStream_t stream) {
    const float* x = (const float*)d_in[0];
    const int* ei = (const int*)d_in[1];
    const float* W1l = (const float*)d_in[2];
    const float* b1 = (const float*)d_in[3];
    const float* W1r = (const float*)d_in[4];
    const float* W2l = (const float*)d_in[5];
    const float* b2 = (const float*)d_in[6];
    const float* W2r = (const float*)d_in[7];
    float* out = (float*)d_out;

    // padded layout: flag 256 | bin_cnt 512 | bins 4.8M | srcs16 6.4M | cnt 200K
    // | wt 512K | xb 12.8M | hb 12.8M
    const size_t padded_need = 256 + 512 + (size_t)NBIN * BIN_CAP * 4 +
                               (size_t)50176 * CAP * 2 + 50048 * 4 + 4 * 65536 +
                               2 * (size_t)N_NODES * D * 2;

    if (ws_size >= padded_need) {
        char* w = (char*)d_ws;
        int* flag = (int*)w;                      w += 256;
        int* bin_cnt = (int*)w;                   w += 512;
        unsigned* bins = (unsigned*)w;            w += (size_t)NBIN * BIN_CAP * 4;
        unsigned short* srcs16 = (unsigned short*)w; w += (size_t)50176 * CAP * 2;
        int* cnt = (int*)w;                       w += 50048 * 4;
        unsigned short* wt1hi = (unsigned short*)w; w += 65536;
        unsigned short* wt1lo = (unsigned short*)w; w += 65536;
        unsigned short* wt2hi = (unsigned short*)w; w += 65536;
        unsigned short* wt2lo = (unsigned short*)w; w += 65536;
        unsigned short* xb = (unsigned short*)w;  w += (size_t)N_NODES * D * 2;
        unsigned short* hb = (unsigned short*)w;

        initp_kernel<<<1, 256, 0, stream>>>(ei, flag, bin_cnt);
        prep_w<<<128, 256, 0, stream>>>(W1l, W1r, wt1hi, wt1lo);
        prep_w<<<128, 256, 0, stream>>>(W2l, W2r, wt2hi, wt2lo);
        tobf_kernel<<<(N_NODES * D / 8 + 255) / 256, 256, 0, stream>>>(x, xb, N_NODES * D / 8);
        binp_kernel<<<(N_EDGES + EPB - 1) / EPB, 256, 0, stream>>>(ei, flag, bin_cnt, bins);
        unbin_kernel<<<NBIN, 256, 0, stream>>>(bin_cnt, bins, cnt, srcs16);

        int nblk = (N_NODES + 63) / 64;
        layer_kernel<1><<<nblk, 256, 3 * 8192 * 2, stream>>>(
            xb, x, nullptr, cnt, srcs16, wt1hi, wt1lo, b1, nullptr, hb);
        layer_kernel<2><<<nblk, 256, 2 * 8192 * 2, stream>>>(
            hb, nullptr, hb, cnt, srcs16, wt2hi, wt2lo, b2, out, nullptr);
    } else {
        // compact CSR fallback
        char* w = (char*)d_ws;
        int* flag = (int*)w;                      w += 256;
        int* cur = (int*)w;                       w += 50048 * 4;
        int* off = (int*)w;                       w += 50056 * 4;
        int* srcs = (int*)w;                      w += (size_t)N_EDGES * 4;
        unsigned short* wt1hi = (unsigned short*)w; w += 65536;
        unsigned short* wt1lo = (unsigned short*)w; w += 65536;
        unsigned short* wt2hi = (unsigned short*)w; w += 65536;
        unsigned short* wt2lo = (unsigned short*)w; w += 65536;
        unsigned short* xb = (unsigned short*)w;  w += (size_t)N_NODES * D * 2;
        unsigned short* aggb = (unsigned short*)w;

        initc_kernel<<<196, 256, 0, stream>>>(ei, flag, cur);
        prep_w<<<128, 256, 0, stream>>>(W1l, W1r, wt1hi, wt1lo);
        prep_w<<<128, 256, 0, stream>>>(W2l, W2r, wt2hi, wt2lo);
        tobf_kernel<<<(N_NODES * D / 8 + 255) / 256, 256, 0, stream>>>(x, xb, N_NODES * D / 8);
        hist_kernel<<<(N_EDGES + 255) / 256, 256, 0, stream>>>(ei, flag, cur);
        scan_kernel<<<1, 1024, 0, stream>>>(cur, off);
        fillc_kernel<<<(N_EDGES + 255) / 256, 256, 0, stream>>>(ei, flag, cur, srcs);

        aggc_kernel<<<(N_NODES + 3) / 4, 256, 0, stream>>>(xb, off, srcs, aggb);
        mm_kernel<1><<<(N_NODES + 63) / 64, 256, 0, stream>>>(aggb, x, nullptr, wt1hi, wt1lo, b1, nullptr, xb);

        aggc_kernel<<<(N_NODES + 3) / 4, 256, 0, stream>>>(xb, off, srcs, aggb);
        mm_kernel<2><<<(N_NODES + 63) / 64, 256, 0, stream>>>(aggb, nullptr, xb, wt2hi, wt2lo, b2, out, nullptr);
    }
}

// Round 7
// 159.033 us; speedup vs baseline: 1.1766x; 1.1766x over previous
//
#include <hip/hip_runtime.h>

#define N_NODES 50000
#define N_EDGES 800000
#define D 128
#define CAP 64
#define NPB 512        // nodes per bin: bin = dst >> 9
#define NBIN 98        // ceil(50000/512)
#define BIN_CAP 12288  // per-bin edge capacity (mean 8163)
#define EPB 4096       // edges per binp block

typedef __attribute__((ext_vector_type(8))) short s16x8;
typedef __attribute__((ext_vector_type(8))) unsigned short u16x8;
typedef __attribute__((ext_vector_type(4))) unsigned short u16x4;
typedef __attribute__((ext_vector_type(4))) float f32x4;

__device__ __forceinline__ unsigned short f2bf(float f) {
    unsigned u = __builtin_bit_cast(unsigned, f);
    return (unsigned short)((u + 0x7FFFu + ((u >> 16) & 1u)) >> 16);
}
__device__ __forceinline__ float bf2f(unsigned short h) {
    return __builtin_bit_cast(float, (unsigned)h << 16);
}

// ---------------------------------------------------------------------------
__global__ void initp_kernel(const int* __restrict__ ei, int* __restrict__ flag,
                             int* __restrict__ bin_cnt) {
    if (threadIdx.x < 128) bin_cnt[threadIdx.x] = 0;
    __shared__ int any;
    if (threadIdx.x == 0) any = 0;
    __syncthreads();
    if (ei[2 * threadIdx.x + 1] != 0) atomicOr(&any, 1);
    __syncthreads();
    if (threadIdx.x == 0) flag[0] = any;
}

__global__ void initc_kernel(const int* __restrict__ ei, int* __restrict__ flag,
                             int* __restrict__ cnt) {
    int i = blockIdx.x * 256 + threadIdx.x;
    if (i < 50048) cnt[i] = 0;
    if (blockIdx.x == 0) {
        __shared__ int any;
        if (threadIdx.x == 0) any = 0;
        __syncthreads();
        if (ei[2 * threadIdx.x + 1] != 0) atomicOr(&any, 1);
        __syncthreads();
        if (threadIdx.x == 0) flag[0] = any;
    }
}

__device__ __forceinline__ int load_src(const int* ei, int is32, int e) {
    return is32 ? ei[e] : ei[2 * e];
}
__device__ __forceinline__ int load_dst(const int* ei, int is32, int e) {
    return is32 ? ei[N_EDGES + e] : ei[2 * N_EDGES + 2 * e];
}

// f32 -> bf16 row-copy (x -> xb).
__global__ void tobf_kernel(const float* __restrict__ in, unsigned short* __restrict__ out,
                            int n8) {
    int t = blockIdx.x * 256 + threadIdx.x;
    if (t >= n8) return;
    float4 a = *(const float4*)(in + (size_t)t * 8);
    float4 b = *(const float4*)(in + (size_t)t * 8 + 4);
    u16x8 o;
    o[0] = f2bf(a.x); o[1] = f2bf(a.y); o[2] = f2bf(a.z); o[3] = f2bf(a.w);
    o[4] = f2bf(b.x); o[5] = f2bf(b.y); o[6] = f2bf(b.z); o[7] = f2bf(b.w);
    *(u16x8*)(out + (size_t)t * 8) = o;
}

// ---------------------------------------------------------------------------
// Pass 1: bin edges by dst>>9 into 98 global bins; packed (dst16|src16).
__global__ __launch_bounds__(256) void binp_kernel(const int* __restrict__ ei,
                                                   const int* __restrict__ flag,
                                                   int* __restrict__ bin_cnt,
                                                   unsigned* __restrict__ bins) {
    __shared__ unsigned sBuf[EPB];
    __shared__ int bcnt[128], brun[128], bpos[128], gbase[128];
    int tid = threadIdx.x;
    int blk = blockIdx.x;
    int e0 = blk * EPB + tid * 16;
    int nblk = N_EDGES - blk * EPB;
    if (nblk > EPB) nblk = EPB;
    bool valid = (tid * 16) < nblk;
    if (tid < 128) bcnt[tid] = 0;
    __syncthreads();
    unsigned packed[16];
    if (valid) {
        int is32 = flag[0];
        if (is32) {
            const int4* ps = (const int4*)(ei + e0);
            const int4* pd = (const int4*)(ei + N_EDGES + e0);
#pragma unroll
            for (int q = 0; q < 4; ++q) {
                int4 s = ps[q], d = pd[q];
                packed[q * 4 + 0] = ((unsigned)d.x << 16) | (unsigned)s.x;
                packed[q * 4 + 1] = ((unsigned)d.y << 16) | (unsigned)s.y;
                packed[q * 4 + 2] = ((unsigned)d.z << 16) | (unsigned)s.z;
                packed[q * 4 + 3] = ((unsigned)d.w << 16) | (unsigned)s.w;
            }
        } else {
            const int4* ps = (const int4*)(ei + 2 * (size_t)e0);
            const int4* pd = (const int4*)(ei + 2 * (size_t)N_EDGES + 2 * (size_t)e0);
#pragma unroll
            for (int q = 0; q < 8; ++q) {
                int4 s = ps[q], d = pd[q];
                packed[q * 2 + 0] = ((unsigned)d.x << 16) | (unsigned)s.x;
                packed[q * 2 + 1] = ((unsigned)d.z << 16) | (unsigned)s.z;
            }
        }
#pragma unroll
        for (int k = 0; k < 16; ++k) atomicAdd(&bcnt[packed[k] >> 25], 1);
    }
    __syncthreads();
    if (tid < 64) {
        int a = bcnt[2 * tid], b = bcnt[2 * tid + 1];
        int s = a + b;
        int incl = s;
#pragma unroll
        for (int o = 1; o < 64; o <<= 1) {
            int t = __shfl_up(incl, o, 64);
            if (tid >= o) incl += t;
        }
        int pref = incl - s;
        brun[2 * tid] = pref;
        brun[2 * tid + 1] = pref + a;
        bpos[2 * tid] = pref;
        bpos[2 * tid + 1] = pref + a;
    }
    __syncthreads();
    if (valid) {
#pragma unroll
        for (int k = 0; k < 16; ++k) {
            int b = packed[k] >> 25;
            int slot = atomicAdd(&bpos[b], 1);
            sBuf[slot] = packed[k];
        }
    }
    __syncthreads();
    if (tid < 128) {
        int n = bcnt[tid];
        gbase[tid] = n > 0 ? atomicAdd(&bin_cnt[tid], n) : 0;
    }
    __syncthreads();
    for (int i = tid; i < nblk; i += 256) {
        unsigned p = sBuf[i];
        int b = p >> 25;
        int gpos = gbase[b] + (i - brun[b]);
        if (gpos < BIN_CAP) bins[(size_t)b * BIN_CAP + gpos] = p;
    }
}

// Pass 2: one block per bin; buckets in LDS; dense coalesced write-out.
__global__ __launch_bounds__(256) void unbin_kernel(const int* __restrict__ bin_cnt,
                                                    const unsigned* __restrict__ bins,
                                                    int* __restrict__ cnt,
                                                    unsigned short* __restrict__ srcs16) {
    __shared__ unsigned short buck[NPB * CAP];
    __shared__ int lcnt[NPB];
    int tid = threadIdx.x;
    int bn = blockIdx.x;
    int nbase = bn * NPB;
    for (int i = tid; i < NPB; i += 256) lcnt[i] = 0;
    __syncthreads();
    int nE = bin_cnt[bn];
    if (nE > BIN_CAP) nE = BIN_CAP;
    for (int i = tid; i < nE; i += 256) {
        unsigned p = bins[(size_t)bn * BIN_CAP + i];
        int local = (int)(p >> 16) - nbase;
        if ((unsigned)local < NPB) {
            int slot = atomicAdd(&lcnt[local], 1);
            if (slot < CAP) buck[local * CAP + slot] = (unsigned short)(p & 0xFFFFu);
        }
    }
    __syncthreads();
    int nlim = N_NODES - nbase;
    if (nlim > NPB) nlim = NPB;
    const uint4* sb = (const uint4*)buck;
    uint4* go = (uint4*)(srcs16 + (size_t)nbase * CAP);
    int n4 = nlim * 8;
    for (int i = tid; i < n4; i += 256) go[i] = sb[i];
    for (int i = tid; i < nlim; i += 256) cnt[nbase + i] = lcnt[i];
}

// ---------------------------------------------------------------------------
// Both W tables in one launch: Wt = [Wl;Wr]^T as bf16 hi(trunc)/lo(RN resid),
// layout [col(128)][k(256)]. Blocks 0-127: layer1; 128-255: layer2.
__global__ void prep_w2(const float* __restrict__ W1l, const float* __restrict__ W1r,
                        const float* __restrict__ W2l, const float* __restrict__ W2r,
                        unsigned short* __restrict__ hi1, unsigned short* __restrict__ lo1,
                        unsigned short* __restrict__ hi2, unsigned short* __restrict__ lo2) {
    int layer = blockIdx.x >> 7;
    int c = blockIdx.x & 127;
    int k = threadIdx.x;
    const float* Wl = layer ? W2l : W1l;
    const float* Wr = layer ? W2r : W1r;
    unsigned short* hi = layer ? hi2 : hi1;
    unsigned short* lo = layer ? lo2 : lo1;
    float v = (k < 128) ? Wl[(size_t)k * 128 + c] : Wr[(size_t)(k - 128) * 128 + c];
    unsigned u = __builtin_bit_cast(unsigned, v);
    unsigned short h = (unsigned short)(u >> 16);
    float hf = __builtin_bit_cast(float, u & 0xFFFF0000u);
    float r = v - hf;
    unsigned ur = __builtin_bit_cast(unsigned, r);
    unsigned short l = (unsigned short)((ur + 0x7FFFu + ((ur >> 16) & 1u)) >> 16);
    hi[c * 256 + k] = h;
    lo[c * 256 + k] = l;
}

// ---------------------------------------------------------------------------
// Padded-path gather-mean over bf16 features, ushort indices. One wave/node.
__global__ __launch_bounds__(256) void aggp_kernel(const unsigned short* __restrict__ feat,
                                                   const int* __restrict__ cnt,
                                                   const unsigned short* __restrict__ srcs16,
                                                   unsigned short* __restrict__ agg) {
    int node = blockIdx.x * 4 + (threadIdx.x >> 6);
    if (node >= N_NODES) return;
    int lane = threadIdx.x & 63;
    int q = lane >> 4;
    int c16 = lane & 15;
    int deg = cnt[node];
    int idx = srcs16[node * CAP + lane];
    int d = deg < CAP ? deg : CAP;
    float acc[8] = {};
    for (int j = 0; j < d; j += 16) {
        int e[4];
        float m[4];
#pragma unroll
        for (int u = 0; u < 4; ++u) {
            int jj = j + u * 4 + q;
            int es = __shfl(idx, jj, 64);
            bool val = jj < d;
            e[u] = val ? es : 0;
            m[u] = val ? 1.f : 0.f;
        }
        u16x8 v[4];
#pragma unroll
        for (int u = 0; u < 4; ++u)
            v[u] = *((const u16x8*)(feat + (size_t)e[u] * D) + c16);
#pragma unroll
        for (int u = 0; u < 4; ++u)
#pragma unroll
            for (int i = 0; i < 8; ++i)
                acc[i] += bf2f((unsigned short)v[u][i]) * m[u];
    }
#pragma unroll
    for (int i = 0; i < 8; ++i) {
        acc[i] += __shfl_xor(acc[i], 16, 64);
        acc[i] += __shfl_xor(acc[i], 32, 64);
    }
    if (q == 0) {
        float s = deg > 0 ? 1.f / (float)deg : 0.f;
        u16x8 o;
#pragma unroll
        for (int i = 0; i < 8; ++i) o[i] = f2bf(acc[i] * s);
        *((u16x8*)(agg + (size_t)node * D) + c16) = o;
    }
}

// ---------------------------------------------------------------------------
// mm2: C[r] = Agb[r] @ W[0:128] + Rootb[r] @ W[128:256] + bias  (+relu MODE1)
// All-bf16 A operands; B = hi/lo split (2 MFMA per frag) -> near-f32 on W.
// 32-row tile, 1563 blocks; 4 waves each own 32 cols; ONE __syncthreads.
// LDS sA[2][32][128] bf16, XOR-swizzled 16B chunks (chunk ^= row&7):
// quarter-wave frag reads = 2-way alias (free), staging writes 2-way (free).
// MODE 1: writes bf16 h to Cb only.  MODE 2: writes f32 to C.
template <int MODE>
__global__ __launch_bounds__(256) void mm2_kernel(const unsigned short* __restrict__ Agb,
                                                  const unsigned short* __restrict__ Rootb,
                                                  const unsigned short* __restrict__ Wthi,
                                                  const unsigned short* __restrict__ Wtlo,
                                                  const float* __restrict__ bias,
                                                  float* __restrict__ C,
                                                  unsigned short* __restrict__ Cb) {
    __shared__ __align__(16) unsigned short sA[2][32][128];
    int r0 = blockIdx.x * 32;
    int tid = threadIdx.x;
    int lane = tid & 63, wid = tid >> 6;
    int l15 = lane & 15, khalf = lane >> 4;

    // ---- stage both A panels (coalesced 32 B/thread/panel)
    {
        int r = tid >> 3;   // 0..31
        int kq = tid & 7;   // 0..7, 16 ushorts each
        int row = r0 + r;
        u16x8 a0, a1, x0, x1;
        if (row < N_NODES) {
            const u16x8* pa = (const u16x8*)(Agb + (size_t)row * D + kq * 16);
            a0 = pa[0]; a1 = pa[1];
            const u16x8* pr = (const u16x8*)(Rootb + (size_t)row * D + kq * 16);
            x0 = pr[0]; x1 = pr[1];
        } else {
            u16x8 z = {};
            a0 = z; a1 = z; x0 = z; x1 = z;
        }
        int c0 = (kq * 2) ^ (r & 7), c1 = (kq * 2 + 1) ^ (r & 7);
        *(u16x8*)&sA[0][r][c0 * 8] = a0;
        *(u16x8*)&sA[0][r][c1 * 8] = a1;
        *(u16x8*)&sA[1][r][c0 * 8] = x0;
        *(u16x8*)&sA[1][r][c1 * 8] = x1;
    }
    __syncthreads();

    // ---- MFMA: p=0 agg (k 0..127), p=1 root (k 128..255)
    f32x4 acc[2][2] = {};
#pragma unroll
    for (int p = 0; p < 2; ++p)
#pragma unroll
        for (int kc2 = 0; kc2 < 4; ++kc2) {
            s16x8 aF[2];
#pragma unroll
            for (int mf = 0; mf < 2; ++mf) {
                int rr = mf * 16 + l15;
                int chunk = (kc2 * 4 + khalf) ^ (rr & 7);
                aF[mf] = *(const s16x8*)&sA[p][rr][chunk * 8];
            }
#pragma unroll
            for (int nf = 0; nf < 2; ++nf) {
                int cc = wid * 32 + nf * 16 + l15;
                size_t bo = (size_t)cc * 256 + p * 128 + kc2 * 32 + khalf * 8;
                s16x8 bH = *(const s16x8*)(Wthi + bo);
                s16x8 bL = *(const s16x8*)(Wtlo + bo);
#pragma unroll
                for (int mf = 0; mf < 2; ++mf) {
                    acc[mf][nf] = __builtin_amdgcn_mfma_f32_16x16x32_bf16(aF[mf], bH, acc[mf][nf], 0, 0, 0);
                    acc[mf][nf] = __builtin_amdgcn_mfma_f32_16x16x32_bf16(aF[mf], bL, acc[mf][nf], 0, 0, 0);
                }
            }
        }

    // ---- epilogue: C/D layout col=lane&15, row=(lane>>4)*4+reg (m89-verified)
#pragma unroll
    for (int mf = 0; mf < 2; ++mf)
#pragma unroll
        for (int nf = 0; nf < 2; ++nf) {
            int col = wid * 32 + nf * 16 + l15;
            float b = bias[col];
#pragma unroll
            for (int r = 0; r < 4; ++r) {
                int row = r0 + mf * 16 + khalf * 4 + r;
                if (row < N_NODES) {
                    float o = acc[mf][nf][r] + b;
                    if (MODE == 1) {
                        o = fmaxf(o, 0.f);
                        Cb[(size_t)row * D + col] = f2bf(o);
                    } else {
                        C[(size_t)row * D + col] = o;
                    }
                }
            }
        }
}

// ---------------------------------------------------------------------------
// ---- compact CSR fallback kernels (only if ws too small) -------------------
__global__ void hist_kernel(const int* __restrict__ ei, const int* __restrict__ flag,
                            int* __restrict__ cnt) {
    int e = blockIdx.x * blockDim.x + threadIdx.x;
    if (e >= N_EDGES) return;
    int is32 = flag[0];
    atomicAdd(&cnt[load_dst(ei, is32, e)], 1);
}

__global__ __launch_bounds__(1024) void scan_kernel(int* __restrict__ cnt_cur,
                                                    int* __restrict__ off) {
    __shared__ int wsum[16];
    __shared__ int woff[16];
    __shared__ int carry;
    __shared__ int tile_tot;
    int lane = threadIdx.x & 63;
    int wid = threadIdx.x >> 6;
    if (threadIdx.x == 0) carry = 0;
    __syncthreads();
    for (int base = 0; base < N_NODES; base += 1024) {
        int i = base + threadIdx.x;
        int v = (i < N_NODES) ? cnt_cur[i] : 0;
        int incl = v;
#pragma unroll
        for (int o = 1; o < 64; o <<= 1) {
            int t = __shfl_up(incl, o, 64);
            if (lane >= o) incl += t;
        }
        if (lane == 63) wsum[wid] = incl;
        __syncthreads();
        if (wid == 0 && lane < 16) {
            int t = wsum[lane];
            int inc2 = t;
#pragma unroll
            for (int o = 1; o < 16; o <<= 1) {
                int u = __shfl_up(inc2, o, 64);
                if (lane >= o) inc2 += u;
            }
            woff[lane] = inc2 - t;
            if (lane == 15) tile_tot = inc2;
        }
        __syncthreads();
        int c = carry;
        if (i < N_NODES) {
            int o = c + woff[wid] + (incl - v);
            off[i] = o;
            cnt_cur[i] = o;
        }
        __syncthreads();
        if (threadIdx.x == 0) carry = c + tile_tot;
        __syncthreads();
    }
    if (threadIdx.x == 0) off[N_NODES] = carry;
}

__global__ void fillc_kernel(const int* __restrict__ ei, const int* __restrict__ flag,
                             int* __restrict__ cur, int* __restrict__ srcs) {
    int e = blockIdx.x * blockDim.x + threadIdx.x;
    if (e >= N_EDGES) return;
    int is32 = flag[0];
    int d = load_dst(ei, is32, e);
    int p = atomicAdd(&cur[d], 1);
    srcs[p] = load_src(ei, is32, e);
}

__global__ __launch_bounds__(256) void aggc_kernel(const unsigned short* __restrict__ feat,
                                                   const int* __restrict__ off,
                                                   const int* __restrict__ srcs,
                                                   unsigned short* __restrict__ agg) {
    int node = blockIdx.x * 4 + (threadIdx.x >> 6);
    if (node >= N_NODES) return;
    int lane = threadIdx.x & 63;
    int half = lane >> 5;
    int c8 = lane & 31;
    int s0 = off[node], s1 = off[node + 1];
    int deg = s1 - s0;
    float a0 = 0.f, a1 = 0.f, a2 = 0.f, a3 = 0.f;
    for (int j = s0; j < s1; j += 2) {
        int jj = j + half;
        if (jj < s1) {
            int e = srcs[jj];
            u16x4 v = *((const u16x4*)(feat + (size_t)e * D) + c8);
            a0 += bf2f((unsigned short)v[0]);
            a1 += bf2f((unsigned short)v[1]);
            a2 += bf2f((unsigned short)v[2]);
            a3 += bf2f((unsigned short)v[3]);
        }
    }
    a0 += __shfl_xor(a0, 32, 64);
    a1 += __shfl_xor(a1, 32, 64);
    a2 += __shfl_xor(a2, 32, 64);
    a3 += __shfl_xor(a3, 32, 64);
    if (half == 0) {
        float s = deg > 0 ? 1.f / (float)deg : 0.f;
        u16x4 o;
        o[0] = f2bf(a0 * s); o[1] = f2bf(a1 * s);
        o[2] = f2bf(a2 * s); o[3] = f2bf(a3 * s);
        *((u16x4*)(agg + (size_t)node * D) + c8) = o;
    }
}

// ---------------------------------------------------------------------------
extern "C" void kernel_launch(void* const* d_in, const int* in_sizes, int n_in,
                              void* d_out, int out_size, void* d_ws, size_t ws_size,
                              hipStream_t stream) {
    const float* x = (const float*)d_in[0];
    const int* ei = (const int*)d_in[1];
    const float* W1l = (const float*)d_in[2];
    const float* b1 = (const float*)d_in[3];
    const float* W1r = (const float*)d_in[4];
    const float* W2l = (const float*)d_in[5];
    const float* b2 = (const float*)d_in[6];
    const float* W2r = (const float*)d_in[7];
    float* out = (float*)d_out;

    // padded layout: flag 256 | bin_cnt 512 | bins 4.8M | srcs16 6.4M | cnt 200K
    // | wt 512K | xb 12.8M | hb 12.8M | aggb 12.8M
    const size_t padded_need = 256 + 512 + (size_t)NBIN * BIN_CAP * 4 +
                               (size_t)50176 * CAP * 2 + 50048 * 4 + 4 * 65536 +
                               3 * (size_t)N_NODES * D * 2;

    if (ws_size >= padded_need) {
        char* w = (char*)d_ws;
        int* flag = (int*)w;                      w += 256;
        int* bin_cnt = (int*)w;                   w += 512;
        unsigned* bins = (unsigned*)w;            w += (size_t)NBIN * BIN_CAP * 4;
        unsigned short* srcs16 = (unsigned short*)w; w += (size_t)50176 * CAP * 2;
        int* cnt = (int*)w;                       w += 50048 * 4;
        unsigned short* wt1hi = (unsigned short*)w; w += 65536;
        unsigned short* wt1lo = (unsigned short*)w; w += 65536;
        unsigned short* wt2hi = (unsigned short*)w; w += 65536;
        unsigned short* wt2lo = (unsigned short*)w; w += 65536;
        unsigned short* xb = (unsigned short*)w;  w += (size_t)N_NODES * D * 2;
        unsigned short* hb = (unsigned short*)w;  w += (size_t)N_NODES * D * 2;
        unsigned short* aggb = (unsigned short*)w;

        initp_kernel<<<1, 256, 0, stream>>>(ei, flag, bin_cnt);
        prep_w2<<<256, 256, 0, stream>>>(W1l, W1r, W2l, W2r, wt1hi, wt1lo, wt2hi, wt2lo);
        tobf_kernel<<<(N_NODES * D / 8 + 255) / 256, 256, 0, stream>>>(x, xb, N_NODES * D / 8);
        binp_kernel<<<(N_EDGES + EPB - 1) / EPB, 256, 0, stream>>>(ei, flag, bin_cnt, bins);
        unbin_kernel<<<NBIN, 256, 0, stream>>>(bin_cnt, bins, cnt, srcs16);

        int nblk = (N_NODES + 31) / 32;
        aggp_kernel<<<(N_NODES + 3) / 4, 256, 0, stream>>>(xb, cnt, srcs16, aggb);
        mm2_kernel<1><<<nblk, 256, 0, stream>>>(aggb, xb, wt1hi, wt1lo, b1, nullptr, hb);

        aggp_kernel<<<(N_NODES + 3) / 4, 256, 0, stream>>>(hb, cnt, srcs16, aggb);
        mm2_kernel<2><<<nblk, 256, 0, stream>>>(aggb, hb, wt2hi, wt2lo, b2, out, nullptr);
    } else {
        // compact CSR fallback (xb doubles as h storage after layer-1 gather)
        char* w = (char*)d_ws;
        int* flag = (int*)w;                      w += 256;
        int* cur = (int*)w;                       w += 50048 * 4;
        int* off = (int*)w;                       w += 50056 * 4;
        int* srcs = (int*)w;                      w += (size_t)N_EDGES * 4;
        unsigned short* wt1hi = (unsigned short*)w; w += 65536;
        unsigned short* wt1lo = (unsigned short*)w; w += 65536;
        unsigned short* wt2hi = (unsigned short*)w; w += 65536;
        unsigned short* wt2lo = (unsigned short*)w; w += 65536;
        unsigned short* xb = (unsigned short*)w;  w += (size_t)N_NODES * D * 2;
        unsigned short* aggb = (unsigned short*)w;

        initc_kernel<<<196, 256, 0, stream>>>(ei, flag, cur);
        prep_w2<<<256, 256, 0, stream>>>(W1l, W1r, W2l, W2r, wt1hi, wt1lo, wt2hi, wt2lo);
        tobf_kernel<<<(N_NODES * D / 8 + 255) / 256, 256, 0, stream>>>(x, xb, N_NODES * D / 8);
        hist_kernel<<<(N_EDGES + 255) / 256, 256, 0, stream>>>(ei, flag, cur);
        scan_kernel<<<1, 1024, 0, stream>>>(cur, off);
        fillc_kernel<<<(N_EDGES + 255) / 256, 256, 0, stream>>>(ei, flag, cur, srcs);

        int nblk = (N_NODES + 31) / 32;
        aggc_kernel<<<(N_NODES + 3) / 4, 256, 0, stream>>>(xb, off, srcs, aggb);
        // write h into xb (safe: gather of xb complete; mm2 reads xb root rows
        // and writes the same rows' h after the final barrier-free epilogue —
        // row-exclusive ownership per block, reads happen before writes per block)
        mm2_kernel<1><<<nblk, 256, 0, stream>>>(aggb, xb, wt1hi, wt1lo, b1, nullptr, xb);

        aggc_kernel<<<(N_NODES + 3) / 4, 256, 0, stream>>>(xb, off, srcs, aggb);
        mm2_kernel<2><<<nblk, 256, 0, stream>>>(aggb, xb, wt2hi, wt2lo, b2, out, nullptr);
    }
}

// Round 8
// 127.026 us; speedup vs baseline: 1.4731x; 1.2520x over previous
//
#include <hip/hip_runtime.h>

#define N_NODES 50000
#define N_EDGES 800000
#define D 128
#define CAP 64
#define NPB 512        // nodes per bin: bin = dst >> 9
#define NBIN 98        // ceil(50000/512)
#define BIN_CAP 12288  // per-bin edge capacity (mean 8163)
#define EPB 4096       // edges per binp block

typedef __attribute__((ext_vector_type(8))) short s16x8;
typedef __attribute__((ext_vector_type(8))) unsigned short u16x8;
typedef __attribute__((ext_vector_type(4))) unsigned short u16x4;
typedef __attribute__((ext_vector_type(4))) float f32x4;

__device__ __forceinline__ unsigned short f2bf(float f) {
    unsigned u = __builtin_bit_cast(unsigned, f);
    return (unsigned short)((u + 0x7FFFu + ((u >> 16) & 1u)) >> 16);
}
__device__ __forceinline__ float bf2f(unsigned short h) {
    return __builtin_bit_cast(float, (unsigned)h << 16);
}

__device__ __forceinline__ int load_src(const int* ei, int is32, int e) {
    return is32 ? ei[e] : ei[2 * e];
}
__device__ __forceinline__ int load_dst(const int* ei, int is32, int e) {
    return is32 ? ei[N_EDGES + e] : ei[2 * N_EDGES + 2 * e];
}

// ---------------------------------------------------------------------------
// Merged prep: blocks 0..3124 = x->bf16; 3125..3380 = W tables (bf16 RN,
// layout [col(128)][k(256)]); 3381 = zero bin_cnt + ei dtype detect.
__global__ void prep_kernel(const float* __restrict__ x, const int* __restrict__ ei,
                            const float* __restrict__ W1l, const float* __restrict__ W1r,
                            const float* __restrict__ W2l, const float* __restrict__ W2r,
                            unsigned short* __restrict__ xb,
                            unsigned short* __restrict__ wt1,
                            unsigned short* __restrict__ wt2,
                            int* __restrict__ flag, int* __restrict__ bin_cnt) {
    int b = blockIdx.x;
    if (b < 3125) {
        int t = b * 256 + threadIdx.x;  // t < 800000 == 3125*256
        float4 a = *(const float4*)(x + (size_t)t * 8);
        float4 c = *(const float4*)(x + (size_t)t * 8 + 4);
        u16x8 o;
        o[0] = f2bf(a.x); o[1] = f2bf(a.y); o[2] = f2bf(a.z); o[3] = f2bf(a.w);
        o[4] = f2bf(c.x); o[5] = f2bf(c.y); o[6] = f2bf(c.z); o[7] = f2bf(c.w);
        *(u16x8*)(xb + (size_t)t * 8) = o;
    } else if (b < 3381) {
        int idx = b - 3125;  // 0..255
        int layer = idx >> 7;
        int c = idx & 127;
        int k = threadIdx.x;
        const float* Wl = layer ? W2l : W1l;
        const float* Wr = layer ? W2r : W1r;
        unsigned short* wt = layer ? wt2 : wt1;
        float v = (k < 128) ? Wl[(size_t)k * 128 + c] : Wr[(size_t)(k - 128) * 128 + c];
        wt[c * 256 + k] = f2bf(v);
    } else {
        if (threadIdx.x < 128) bin_cnt[threadIdx.x] = 0;
        __shared__ int any;
        if (threadIdx.x == 0) any = 0;
        __syncthreads();
        if (ei[2 * threadIdx.x + 1] != 0) atomicOr(&any, 1);
        __syncthreads();
        if (threadIdx.x == 0) flag[0] = any;
    }
}

// ---------------------------------------------------------------------------
// Pass 1: bin edges by dst>>9 into 98 global bins; packed (dst16|src16).
__global__ __launch_bounds__(256) void binp_kernel(const int* __restrict__ ei,
                                                   const int* __restrict__ flag,
                                                   int* __restrict__ bin_cnt,
                                                   unsigned* __restrict__ bins) {
    __shared__ unsigned sBuf[EPB];
    __shared__ int bcnt[128], brun[128], bpos[128], gbase[128];
    int tid = threadIdx.x;
    int blk = blockIdx.x;
    int e0 = blk * EPB + tid * 16;
    int nblk = N_EDGES - blk * EPB;
    if (nblk > EPB) nblk = EPB;
    bool valid = (tid * 16) < nblk;
    if (tid < 128) bcnt[tid] = 0;
    __syncthreads();
    unsigned packed[16];
    if (valid) {
        int is32 = flag[0];
        if (is32) {
            const int4* ps = (const int4*)(ei + e0);
            const int4* pd = (const int4*)(ei + N_EDGES + e0);
#pragma unroll
            for (int q = 0; q < 4; ++q) {
                int4 s = ps[q], d = pd[q];
                packed[q * 4 + 0] = ((unsigned)d.x << 16) | (unsigned)s.x;
                packed[q * 4 + 1] = ((unsigned)d.y << 16) | (unsigned)s.y;
                packed[q * 4 + 2] = ((unsigned)d.z << 16) | (unsigned)s.z;
                packed[q * 4 + 3] = ((unsigned)d.w << 16) | (unsigned)s.w;
            }
        } else {
            const int4* ps = (const int4*)(ei + 2 * (size_t)e0);
            const int4* pd = (const int4*)(ei + 2 * (size_t)N_EDGES + 2 * (size_t)e0);
#pragma unroll
            for (int q = 0; q < 8; ++q) {
                int4 s = ps[q], d = pd[q];
                packed[q * 2 + 0] = ((unsigned)d.x << 16) | (unsigned)s.x;
                packed[q * 2 + 1] = ((unsigned)d.z << 16) | (unsigned)s.z;
            }
        }
#pragma unroll
        for (int k = 0; k < 16; ++k) atomicAdd(&bcnt[packed[k] >> 25], 1);
    }
    __syncthreads();
    if (tid < 64) {
        int a = bcnt[2 * tid], b = bcnt[2 * tid + 1];
        int s = a + b;
        int incl = s;
#pragma unroll
        for (int o = 1; o < 64; o <<= 1) {
            int t = __shfl_up(incl, o, 64);
            if (tid >= o) incl += t;
        }
        int pref = incl - s;
        brun[2 * tid] = pref;
        brun[2 * tid + 1] = pref + a;
        bpos[2 * tid] = pref;
        bpos[2 * tid + 1] = pref + a;
    }
    __syncthreads();
    if (valid) {
#pragma unroll
        for (int k = 0; k < 16; ++k) {
            int b = packed[k] >> 25;
            int slot = atomicAdd(&bpos[b], 1);
            sBuf[slot] = packed[k];
        }
    }
    __syncthreads();
    if (tid < 128) {
        int n = bcnt[tid];
        gbase[tid] = n > 0 ? atomicAdd(&bin_cnt[tid], n) : 0;
    }
    __syncthreads();
    for (int i = tid; i < nblk; i += 256) {
        unsigned p = sBuf[i];
        int b = p >> 25;
        int gpos = gbase[b] + (i - brun[b]);
        if (gpos < BIN_CAP) bins[(size_t)b * BIN_CAP + gpos] = p;
    }
}

// Pass 2: one block per bin; buckets in LDS; dense coalesced write-out.
__global__ __launch_bounds__(256) void unbin_kernel(const int* __restrict__ bin_cnt,
                                                    const unsigned* __restrict__ bins,
                                                    int* __restrict__ cnt,
                                                    unsigned short* __restrict__ srcs16) {
    __shared__ unsigned short buck[NPB * CAP];
    __shared__ int lcnt[NPB];
    int tid = threadIdx.x;
    int bn = blockIdx.x;
    int nbase = bn * NPB;
    for (int i = tid; i < NPB; i += 256) lcnt[i] = 0;
    __syncthreads();
    int nE = bin_cnt[bn];
    if (nE > BIN_CAP) nE = BIN_CAP;
    for (int i = tid; i < nE; i += 256) {
        unsigned p = bins[(size_t)bn * BIN_CAP + i];
        int local = (int)(p >> 16) - nbase;
        if ((unsigned)local < NPB) {
            int slot = atomicAdd(&lcnt[local], 1);
            if (slot < CAP) buck[local * CAP + slot] = (unsigned short)(p & 0xFFFFu);
        }
    }
    __syncthreads();
    int nlim = N_NODES - nbase;
    if (nlim > NPB) nlim = NPB;
    const uint4* sb = (const uint4*)buck;
    uint4* go = (uint4*)(srcs16 + (size_t)nbase * CAP);
    int n4 = nlim * 8;
    for (int i = tid; i < n4; i += 256) go[i] = sb[i];
    for (int i = tid; i < nlim; i += 256) cnt[nbase + i] = lcnt[i];
}

// ---------------------------------------------------------------------------
// Padded-path gather-mean over bf16 features, ushort indices. One wave/node.
__global__ __launch_bounds__(256) void aggp_kernel(const unsigned short* __restrict__ feat,
                                                   const int* __restrict__ cnt,
                                                   const unsigned short* __restrict__ srcs16,
                                                   unsigned short* __restrict__ agg) {
    int node = blockIdx.x * 4 + (threadIdx.x >> 6);
    if (node >= N_NODES) return;
    int lane = threadIdx.x & 63;
    int q = lane >> 4;
    int c16 = lane & 15;
    int deg = cnt[node];
    int idx = srcs16[node * CAP + lane];
    int d = deg < CAP ? deg : CAP;
    float acc[8] = {};
    for (int j = 0; j < d; j += 16) {
        int e[4];
        float m[4];
#pragma unroll
        for (int u = 0; u < 4; ++u) {
            int jj = j + u * 4 + q;
            int es = __shfl(idx, jj, 64);
            bool val = jj < d;
            e[u] = val ? es : 0;
            m[u] = val ? 1.f : 0.f;
        }
        u16x8 v[4];
#pragma unroll
        for (int u = 0; u < 4; ++u)
            v[u] = *((const u16x8*)(feat + (size_t)e[u] * D) + c16);
#pragma unroll
        for (int u = 0; u < 4; ++u)
#pragma unroll
            for (int i = 0; i < 8; ++i)
                acc[i] += bf2f((unsigned short)v[u][i]) * m[u];
    }
#pragma unroll
    for (int i = 0; i < 8; ++i) {
        acc[i] += __shfl_xor(acc[i], 16, 64);
        acc[i] += __shfl_xor(acc[i], 32, 64);
    }
    if (q == 0) {
        float s = deg > 0 ? 1.f / (float)deg : 0.f;
        u16x8 o;
#pragma unroll
        for (int i = 0; i < 8; ++i) o[i] = f2bf(acc[i] * s);
        *((u16x8*)(agg + (size_t)node * D) + c16) = o;
    }
}

// ---------------------------------------------------------------------------
// mm3: C[r] = Agb[r] @ W[0:128] + Rootb[r] @ W[128:256] + bias (+relu MODE1)
// Single-bf16 W (RN), held ENTIRELY in registers (16 frags = 64 VGPR/lane),
// preloaded before the A-staging barrier -> MFMA loop has zero global loads.
// 32-row tile, 1563 blocks, 4 waves x 32 cols, ONE __syncthreads.
// LDS XOR-swizzled 16B chunks (chunk ^= row&7): frag reads 2-way (free).
template <int MODE>
__global__ __launch_bounds__(256) void mm3_kernel(const unsigned short* __restrict__ Agb,
                                                  const unsigned short* __restrict__ Rootb,
                                                  const unsigned short* __restrict__ Wt,
                                                  const float* __restrict__ bias,
                                                  float* __restrict__ C,
                                                  unsigned short* __restrict__ Cb) {
    __shared__ __align__(16) unsigned short sA[2][32][128];
    int r0 = blockIdx.x * 32;
    int tid = threadIdx.x;
    int lane = tid & 63, wid = tid >> 6;
    int l15 = lane & 15, khalf = lane >> 4;

    // ---- preload all B fragments for this wave's 32 cols (issue FIRST)
    s16x8 bF[2][4][2];
#pragma unroll
    for (int p = 0; p < 2; ++p)
#pragma unroll
        for (int kc2 = 0; kc2 < 4; ++kc2)
#pragma unroll
            for (int nf = 0; nf < 2; ++nf) {
                int cc = wid * 32 + nf * 16 + l15;
                bF[p][kc2][nf] = *(const s16x8*)(Wt + (size_t)cc * 256 + p * 128 +
                                                 kc2 * 32 + khalf * 8);
            }

    // ---- stage both A panels (coalesced 32 B/thread/panel)
    {
        int r = tid >> 3;   // 0..31
        int kq = tid & 7;   // 0..7, 16 ushorts each
        int row = r0 + r;
        u16x8 a0, a1, x0, x1;
        if (row < N_NODES) {
            const u16x8* pa = (const u16x8*)(Agb + (size_t)row * D + kq * 16);
            a0 = pa[0]; a1 = pa[1];
            const u16x8* pr = (const u16x8*)(Rootb + (size_t)row * D + kq * 16);
            x0 = pr[0]; x1 = pr[1];
        } else {
            u16x8 z = {};
            a0 = z; a1 = z; x0 = z; x1 = z;
        }
        int c0 = (kq * 2) ^ (r & 7), c1 = (kq * 2 + 1) ^ (r & 7);
        *(u16x8*)&sA[0][r][c0 * 8] = a0;
        *(u16x8*)&sA[0][r][c1 * 8] = a1;
        *(u16x8*)&sA[1][r][c0 * 8] = x0;
        *(u16x8*)&sA[1][r][c1 * 8] = x1;
    }
    __syncthreads();

    // ---- MFMA: p=0 agg (k 0..127), p=1 root (k 128..255); pure LDS+MFMA
    f32x4 acc[2][2] = {};
#pragma unroll
    for (int p = 0; p < 2; ++p)
#pragma unroll
        for (int kc2 = 0; kc2 < 4; ++kc2) {
            s16x8 aF[2];
#pragma unroll
            for (int mf = 0; mf < 2; ++mf) {
                int rr = mf * 16 + l15;
                int chunk = (kc2 * 4 + khalf) ^ (rr & 7);
                aF[mf] = *(const s16x8*)&sA[p][rr][chunk * 8];
            }
#pragma unroll
            for (int nf = 0; nf < 2; ++nf)
#pragma unroll
                for (int mf = 0; mf < 2; ++mf)
                    acc[mf][nf] = __builtin_amdgcn_mfma_f32_16x16x32_bf16(
                        aF[mf], bF[p][kc2][nf], acc[mf][nf], 0, 0, 0);
        }

    // ---- epilogue: C/D layout col=lane&15, row=(lane>>4)*4+reg (m89-verified)
#pragma unroll
    for (int mf = 0; mf < 2; ++mf)
#pragma unroll
        for (int nf = 0; nf < 2; ++nf) {
            int col = wid * 32 + nf * 16 + l15;
            float b = bias[col];
#pragma unroll
            for (int r = 0; r < 4; ++r) {
                int row = r0 + mf * 16 + khalf * 4 + r;
                if (row < N_NODES) {
                    float o = acc[mf][nf][r] + b;
                    if (MODE == 1) {
                        o = fmaxf(o, 0.f);
                        Cb[(size_t)row * D + col] = f2bf(o);
                    } else {
                        C[(size_t)row * D + col] = o;
                    }
                }
            }
        }
}

// ---------------------------------------------------------------------------
// ---- compact CSR fallback kernels (only if ws too small) -------------------
__global__ void initc_kernel(const int* __restrict__ ei, int* __restrict__ flag,
                             int* __restrict__ cnt) {
    int i = blockIdx.x * 256 + threadIdx.x;
    if (i < 50048) cnt[i] = 0;
    if (blockIdx.x == 0) {
        __shared__ int any;
        if (threadIdx.x == 0) any = 0;
        __syncthreads();
        if (ei[2 * threadIdx.x + 1] != 0) atomicOr(&any, 1);
        __syncthreads();
        if (threadIdx.x == 0) flag[0] = any;
    }
}

__global__ void prep_wf_kernel(const float* __restrict__ W1l, const float* __restrict__ W1r,
                               const float* __restrict__ W2l, const float* __restrict__ W2r,
                               unsigned short* __restrict__ wt1,
                               unsigned short* __restrict__ wt2) {
    int layer = blockIdx.x >> 7;
    int c = blockIdx.x & 127;
    int k = threadIdx.x;
    const float* Wl = layer ? W2l : W1l;
    const float* Wr = layer ? W2r : W1r;
    unsigned short* wt = layer ? wt2 : wt1;
    float v = (k < 128) ? Wl[(size_t)k * 128 + c] : Wr[(size_t)(k - 128) * 128 + c];
    wt[c * 256 + k] = f2bf(v);
}

__global__ void tobf_kernel(const float* __restrict__ in, unsigned short* __restrict__ out,
                            int n8) {
    int t = blockIdx.x * 256 + threadIdx.x;
    if (t >= n8) return;
    float4 a = *(const float4*)(in + (size_t)t * 8);
    float4 b = *(const float4*)(in + (size_t)t * 8 + 4);
    u16x8 o;
    o[0] = f2bf(a.x); o[1] = f2bf(a.y); o[2] = f2bf(a.z); o[3] = f2bf(a.w);
    o[4] = f2bf(b.x); o[5] = f2bf(b.y); o[6] = f2bf(b.z); o[7] = f2bf(b.w);
    *(u16x8*)(out + (size_t)t * 8) = o;
}

__global__ void hist_kernel(const int* __restrict__ ei, const int* __restrict__ flag,
                            int* __restrict__ cnt) {
    int e = blockIdx.x * blockDim.x + threadIdx.x;
    if (e >= N_EDGES) return;
    int is32 = flag[0];
    atomicAdd(&cnt[load_dst(ei, is32, e)], 1);
}

__global__ __launch_bounds__(1024) void scan_kernel(int* __restrict__ cnt_cur,
                                                    int* __restrict__ off) {
    __shared__ int wsum[16];
    __shared__ int woff[16];
    __shared__ int carry;
    __shared__ int tile_tot;
    int lane = threadIdx.x & 63;
    int wid = threadIdx.x >> 6;
    if (threadIdx.x == 0) carry = 0;
    __syncthreads();
    for (int base = 0; base < N_NODES; base += 1024) {
        int i = base + threadIdx.x;
        int v = (i < N_NODES) ? cnt_cur[i] : 0;
        int incl = v;
#pragma unroll
        for (int o = 1; o < 64; o <<= 1) {
            int t = __shfl_up(incl, o, 64);
            if (lane >= o) incl += t;
        }
        if (lane == 63) wsum[wid] = incl;
        __syncthreads();
        if (wid == 0 && lane < 16) {
            int t = wsum[lane];
            int inc2 = t;
#pragma unroll
            for (int o = 1; o < 16; o <<= 1) {
                int u = __shfl_up(inc2, o, 64);
                if (lane >= o) inc2 += u;
            }
            woff[lane] = inc2 - t;
            if (lane == 15) tile_tot = inc2;
        }
        __syncthreads();
        int c = carry;
        if (i < N_NODES) {
            int o = c + woff[wid] + (incl - v);
            off[i] = o;
            cnt_cur[i] = o;
        }
        __syncthreads();
        if (threadIdx.x == 0) carry = c + tile_tot;
        __syncthreads();
    }
    if (threadIdx.x == 0) off[N_NODES] = carry;
}

__global__ void fillc_kernel(const int* __restrict__ ei, const int* __restrict__ flag,
                             int* __restrict__ cur, int* __restrict__ srcs) {
    int e = blockIdx.x * blockDim.x + threadIdx.x;
    if (e >= N_EDGES) return;
    int is32 = flag[0];
    int d = load_dst(ei, is32, e);
    int p = atomicAdd(&cur[d], 1);
    srcs[p] = load_src(ei, is32, e);
}

__global__ __launch_bounds__(256) void aggc_kernel(const unsigned short* __restrict__ feat,
                                                   const int* __restrict__ off,
                                                   const int* __restrict__ srcs,
                                                   unsigned short* __restrict__ agg) {
    int node = blockIdx.x * 4 + (threadIdx.x >> 6);
    if (node >= N_NODES) return;
    int lane = threadIdx.x & 63;
    int half = lane >> 5;
    int c8 = lane & 31;
    int s0 = off[node], s1 = off[node + 1];
    int deg = s1 - s0;
    float a0 = 0.f, a1 = 0.f, a2 = 0.f, a3 = 0.f;
    for (int j = s0; j < s1; j += 2) {
        int jj = j + half;
        if (jj < s1) {
            int e = srcs[jj];
            u16x4 v = *((const u16x4*)(feat + (size_t)e * D) + c8);
            a0 += bf2f((unsigned short)v[0]);
            a1 += bf2f((unsigned short)v[1]);
            a2 += bf2f((unsigned short)v[2]);
            a3 += bf2f((unsigned short)v[3]);
        }
    }
    a0 += __shfl_xor(a0, 32, 64);
    a1 += __shfl_xor(a1, 32, 64);
    a2 += __shfl_xor(a2, 32, 64);
    a3 += __shfl_xor(a3, 32, 64);
    if (half == 0) {
        float s = deg > 0 ? 1.f / (float)deg : 0.f;
        u16x4 o;
        o[0] = f2bf(a0 * s); o[1] = f2bf(a1 * s);
        o[2] = f2bf(a2 * s); o[3] = f2bf(a3 * s);
        *((u16x4*)(agg + (size_t)node * D) + c8) = o;
    }
}

// ---------------------------------------------------------------------------
extern "C" void kernel_launch(void* const* d_in, const int* in_sizes, int n_in,
                              void* d_out, int out_size, void* d_ws, size_t ws_size,
                              hipStream_t stream) {
    const float* x = (const float*)d_in[0];
    const int* ei = (const int*)d_in[1];
    const float* W1l = (const float*)d_in[2];
    const float* b1 = (const float*)d_in[3];
    const float* W1r = (const float*)d_in[4];
    const float* W2l = (const float*)d_in[5];
    const float* b2 = (const float*)d_in[6];
    const float* W2r = (const float*)d_in[7];
    float* out = (float*)d_out;

    // padded layout: flag 256 | bin_cnt 512 | bins 4.8M | srcs16 6.4M | cnt 200K
    // | wt1 64K | wt2 64K | xb 12.8M | hb 12.8M | aggb 12.8M
    const size_t padded_need = 256 + 512 + (size_t)NBIN * BIN_CAP * 4 +
                               (size_t)50176 * CAP * 2 + 50048 * 4 + 2 * 65536 +
                               3 * (size_t)N_NODES * D * 2;

    if (ws_size >= padded_need) {
        char* w = (char*)d_ws;
        int* flag = (int*)w;                      w += 256;
        int* bin_cnt = (int*)w;                   w += 512;
        unsigned* bins = (unsigned*)w;            w += (size_t)NBIN * BIN_CAP * 4;
        unsigned short* srcs16 = (unsigned short*)w; w += (size_t)50176 * CAP * 2;
        int* cnt = (int*)w;                       w += 50048 * 4;
        unsigned short* wt1 = (unsigned short*)w; w += 65536;
        unsigned short* wt2 = (unsigned short*)w; w += 65536;
        unsigned short* xb = (unsigned short*)w;  w += (size_t)N_NODES * D * 2;
        unsigned short* hb = (unsigned short*)w;  w += (size_t)N_NODES * D * 2;
        unsigned short* aggb = (unsigned short*)w;

        prep_kernel<<<3382, 256, 0, stream>>>(x, ei, W1l, W1r, W2l, W2r, xb, wt1, wt2,
                                              flag, bin_cnt);
        binp_kernel<<<(N_EDGES + EPB - 1) / EPB, 256, 0, stream>>>(ei, flag, bin_cnt, bins);
        unbin_kernel<<<NBIN, 256, 0, stream>>>(bin_cnt, bins, cnt, srcs16);

        int nblk = (N_NODES + 31) / 32;
        aggp_kernel<<<(N_NODES + 3) / 4, 256, 0, stream>>>(xb, cnt, srcs16, aggb);
        mm3_kernel<1><<<nblk, 256, 0, stream>>>(aggb, xb, wt1, b1, nullptr, hb);

        aggp_kernel<<<(N_NODES + 3) / 4, 256, 0, stream>>>(hb, cnt, srcs16, aggb);
        mm3_kernel<2><<<nblk, 256, 0, stream>>>(aggb, hb, wt2, b2, out, nullptr);
    } else {
        // compact CSR fallback (xb doubles as h storage after layer-1 gather)
        char* w = (char*)d_ws;
        int* flag = (int*)w;                      w += 256;
        int* cur = (int*)w;                       w += 50048 * 4;
        int* off = (int*)w;                       w += 50056 * 4;
        int* srcs = (int*)w;                      w += (size_t)N_EDGES * 4;
        unsigned short* wt1 = (unsigned short*)w; w += 65536;
        unsigned short* wt2 = (unsigned short*)w; w += 65536;
        unsigned short* xb = (unsigned short*)w;  w += (size_t)N_NODES * D * 2;
        unsigned short* aggb = (unsigned short*)w;

        initc_kernel<<<196, 256, 0, stream>>>(ei, flag, cur);
        prep_wf_kernel<<<256, 256, 0, stream>>>(W1l, W1r, W2l, W2r, wt1, wt2);
        tobf_kernel<<<(N_NODES * D / 8 + 255) / 256, 256, 0, stream>>>(x, xb, N_NODES * D / 8);
        hist_kernel<<<(N_EDGES + 255) / 256, 256, 0, stream>>>(ei, flag, cur);
        scan_kernel<<<1, 1024, 0, stream>>>(cur, off);
        fillc_kernel<<<(N_EDGES + 255) / 256, 256, 0, stream>>>(ei, flag, cur, srcs);

        int nblk = (N_NODES + 31) / 32;
        aggc_kernel<<<(N_NODES + 3) / 4, 256, 0, stream>>>(xb, off, srcs, aggb);
        // in-place xb->h safe: each block reads only its own rows before writing them
        mm3_kernel<1><<<nblk, 256, 0, stream>>>(aggb, xb, wt1, b1, nullptr, xb);

        aggc_kernel<<<(N_NODES + 3) / 4, 256, 0, stream>>>(xb, off, srcs, aggb);
        mm3_kernel<2><<<nblk, 256, 0, stream>>>(aggb, xb, wt2, b2, out, nullptr);
    }
}